// Round 1
// baseline (17165.034 us; speedup 1.0000x reference)
//
#include <hip/hip_runtime.h>

#define Tn 512
#define Bn 256
#define Hn 512
#define INn 512

typedef __attribute__((ext_vector_type(8))) short bf16x8;
typedef __attribute__((ext_vector_type(4))) float f32x4;

__device__ __forceinline__ unsigned short f2bf(float f) {
  unsigned int u = __float_as_uint(f);
  unsigned int r = (u + 0x7fffu + ((u >> 16) & 1u)) >> 16;
  return (unsigned short)r;
}

__device__ __forceinline__ float sigm(float x) { return 1.0f / (1.0f + __expf(-x)); }
__device__ __forceinline__ float tanh_f(float x) { return 2.0f / (1.0f + __expf(-2.0f * x)) - 1.0f; }

__device__ __forceinline__ bf16x8 ld8(const unsigned short* p) {
  return *reinterpret_cast<const bf16x8*>(p);
}

__device__ __forceinline__ f32x4 mfma16(bf16x8 a, bf16x8 b, f32x4 c) {
  return __builtin_amdgcn_mfma_f32_16x16x32_bf16(a, b, c, 0, 0, 0);
}

// ---------------- fp32 -> bf16 conversion (grid-stride, x4 vectorized) ----------------
__global__ __launch_bounds__(256) void cvt_kernel(const float* __restrict__ in,
                                                  unsigned short* __restrict__ out, int n) {
  const int stride = gridDim.x * blockDim.x * 4;
  for (int i = (blockIdx.x * blockDim.x + threadIdx.x) * 4; i < n; i += stride) {
    float4 v = *reinterpret_cast<const float4*>(in + i);
    ushort4 o;
    o.x = f2bf(v.x); o.y = f2bf(v.y); o.z = f2bf(v.z); o.w = f2bf(v.w);
    *reinterpret_cast<ushort4*>(out + i) = o;
  }
}

// ---------------- XP = x @ Wx.T + folded biases ----------------
// xb: (M,512) bf16 (M = Tc*256, t-major), Wxb: (2048,512) bf16, XP: (M,2048) fp32
// col order matches Wx rows: [0:512]=z [512:1024]=r [1024:1536]=x_h [1536:2048]=u
// fold: z,r cols get bx+bh+bgh at same index; u cols get bx[col]+bh[col-512]+bgh[col-512]; x_h only bx.
__global__ __launch_bounds__(256) void xp_gemm_kernel(
    const unsigned short* __restrict__ xb,
    const unsigned short* __restrict__ Wxb,
    const float* __restrict__ bx,
    const float* __restrict__ bh,
    const float* __restrict__ bgh,
    float* __restrict__ XP) {
  const int m0 = blockIdx.x * 64;
  const int n0 = blockIdx.y * 64;
  const int wave = threadIdx.x >> 6;
  const int lane = threadIdx.x & 63;
  const int l15 = lane & 15;
  const int lk = (lane >> 4) * 8;
  const int ro = (wave >> 1) * 32;
  const int co = (wave & 1) * 32;
  const unsigned short* ap = xb + (size_t)(m0 + ro + l15) * INn + lk;
  const unsigned short* bp = Wxb + (size_t)(n0 + co + l15) * INn + lk;
  f32x4 acc[2][2] = {};
  for (int k = 0; k < INn; k += 32) {
    bf16x8 a0 = ld8(ap + k);
    bf16x8 a1 = ld8(ap + 16 * INn + k);
    bf16x8 w0 = ld8(bp + k);
    bf16x8 w1 = ld8(bp + 16 * INn + k);
    acc[0][0] = mfma16(a0, w0, acc[0][0]);
    acc[0][1] = mfma16(a0, w1, acc[0][1]);
    acc[1][0] = mfma16(a1, w0, acc[1][0]);
    acc[1][1] = mfma16(a1, w1, acc[1][1]);
  }
#pragma unroll
  for (int rt = 0; rt < 2; ++rt)
#pragma unroll
    for (int ct = 0; ct < 2; ++ct) {
      const int col = n0 + co + ct * 16 + l15;
      float bias = bx[col];
      if (col < 1024) bias += bh[col] + bgh[col];
      else if (col >= 1536) bias += bh[col - 512] + bgh[col - 512];
#pragma unroll
      for (int r = 0; r < 4; ++r) {
        const int row = m0 + ro + rt * 16 + (lane >> 4) * 4 + r;
        XP[(size_t)row * 2048 + col] = acc[rt][ct][r] + bias;
      }
    }
}

// ---------------- phase A: gate GEMMs + h update ----------------
// Semantic blocks (32 cols each at j-slice j0), wave w owns blocks 2w,2w+1:
//  0: Wh  z (row j0)       A=h   1: Wh  r (j0+512)  A=h
//  2: Wh  u (j0+1024)      A=h   3: Wgh z (j0)      A=g
//  4: Wgh r (j0+512)       A=g   5: Wgh u (j0+1024) A=g
//  6: Wg  z2 (j0)          A=g   7: Wg  r2 (j0+512) A=g
__global__ __launch_bounds__(256) void phaseA_kernel(
    const unsigned short* __restrict__ Whb,
    const unsigned short* __restrict__ Wghb,
    const unsigned short* __restrict__ Wgb,
    const unsigned short* __restrict__ hb_in,
    const unsigned short* __restrict__ gb_in,
    const float* __restrict__ XPt,      // (B,2048) fp32, biases folded
    const float* __restrict__ gf,       // (B,H) fp32 master g
    const float* __restrict__ hprev,    // (B,H) fp32 master h(t-1)
    float* __restrict__ hs_out,         // d_out + t*B*H
    float* __restrict__ h_tail,         // d_out tail (t==T-1) or nullptr
    unsigned short* __restrict__ hb_out,
    unsigned short* __restrict__ hdb_out,
    float* __restrict__ PAg) {          // (B,1024): [z2 | r2] raw preacts
  __shared__ float pa[8][32][32];
  const int b0 = blockIdx.x * 32;
  const int j0 = blockIdx.y * 32;
  const int wave = threadIdx.x >> 6;
  const int lane = threadIdx.x & 63;
  const int l15 = lane & 15;
  const int lk = (lane >> 4) * 8;

  const unsigned short* W0 = (wave <= 1) ? Whb : (wave == 2 ? Wghb : Wgb);
  const unsigned short* W1 = (wave == 0) ? Whb : (wave == 3 ? Wgb : Wghb);
  const int OFF0 = (wave == 1) ? 1024 : (wave == 2) ? 512 : 0;
  const int OFF1 = (wave == 0 || wave == 3) ? 512 : (wave == 2) ? 1024 : 0;
  const unsigned short* A0 = (wave <= 1) ? hb_in : gb_in;
  const unsigned short* A1 = (wave == 0) ? hb_in : gb_in;

  const unsigned short* a0p = A0 + (size_t)(b0 + l15) * Hn + lk;
  const unsigned short* a1p = A1 + (size_t)(b0 + l15) * Hn + lk;
  const unsigned short* b0p = W0 + (size_t)(j0 + OFF0 + l15) * Hn + lk;
  const unsigned short* b1p = W1 + (size_t)(j0 + OFF1 + l15) * Hn + lk;

  f32x4 acc[2][2][2] = {};
  for (int k = 0; k < Hn; k += 32) {
    bf16x8 aA0 = ld8(a0p + k);
    bf16x8 aA1 = ld8(a0p + 16 * Hn + k);
    bf16x8 aB0 = ld8(a1p + k);
    bf16x8 aB1 = ld8(a1p + 16 * Hn + k);
    bf16x8 bA0 = ld8(b0p + k);
    bf16x8 bA1 = ld8(b0p + 16 * Hn + k);
    bf16x8 bB0 = ld8(b1p + k);
    bf16x8 bB1 = ld8(b1p + 16 * Hn + k);
    acc[0][0][0] = mfma16(aA0, bA0, acc[0][0][0]);
    acc[0][0][1] = mfma16(aA0, bA1, acc[0][0][1]);
    acc[0][1][0] = mfma16(aA1, bA0, acc[0][1][0]);
    acc[0][1][1] = mfma16(aA1, bA1, acc[0][1][1]);
    acc[1][0][0] = mfma16(aB0, bB0, acc[1][0][0]);
    acc[1][0][1] = mfma16(aB0, bB1, acc[1][0][1]);
    acc[1][1][0] = mfma16(aB1, bB0, acc[1][1][0]);
    acc[1][1][1] = mfma16(aB1, bB1, acc[1][1][1]);
  }
#pragma unroll
  for (int s = 0; s < 2; ++s)
#pragma unroll
    for (int rt = 0; rt < 2; ++rt)
#pragma unroll
      for (int ct = 0; ct < 2; ++ct)
#pragma unroll
        for (int r = 0; r < 4; ++r)
          pa[wave * 2 + s][rt * 16 + (lane >> 4) * 4 + r][ct * 16 + l15] = acc[s][rt][ct][r];
  __syncthreads();

  const int bl = threadIdx.x >> 3;
  const int b = b0 + bl;
  const float* xp = XPt + (size_t)b * 2048;
#pragma unroll
  for (int i = 0; i < 4; ++i) {
    const int jl = (threadIdx.x & 7) * 4 + i;
    const int j = j0 + jl;
    float z = sigm(xp[j] + pa[0][bl][jl] + pa[3][bl][jl]);
    float r = sigm(xp[512 + j] + pa[1][bl][jl] + pa[4][bl][jl]);
    float u = sigm(xp[1536 + j] + pa[2][bl][jl] + pa[5][bl][jl]);
    const size_t o = (size_t)b * Hn + j;
    float hp = hprev[o];
    float gv = gf[o];
    float cand = tanh_f(xp[1024 + j] + r * hp + u * gv);
    float hn = (1.0f - z) * hp + z * cand;
    hs_out[o] = hn;
    if (h_tail) h_tail[o] = hn;
    hb_out[o] = f2bf(hn);
    hdb_out[o] = f2bf(hn - hp);
    PAg[(size_t)b * 1024 + j] = pa[6][bl][jl];
    PAg[(size_t)b * 1024 + 512 + j] = pa[7][bl][jl];
  }
}

// ---------------- phase B: h_d @ Whd.T + g update ----------------
__global__ __launch_bounds__(256) void phaseB_kernel(
    const unsigned short* __restrict__ Whdb,
    const unsigned short* __restrict__ hdb,
    const float* __restrict__ bhd,
    const float* __restrict__ bgv,
    const float* __restrict__ PAg,
    float* __restrict__ gf,
    unsigned short* __restrict__ gb_out,
    float* __restrict__ g_tail) {
  __shared__ float pa[3][32][32];
  const int b0 = blockIdx.x * 32;
  const int j0 = blockIdx.y * 32;
  const int wave = threadIdx.x >> 6;
  const int lane = threadIdx.x & 63;
  const int l15 = lane & 15;
  const int lk = (lane >> 4) * 8;
  if (wave < 3) {
    const unsigned short* ap = hdb + (size_t)(b0 + l15) * Hn + lk;
    const unsigned short* bp = Whdb + (size_t)(j0 + wave * 512 + l15) * Hn + lk;
    f32x4 acc[2][2] = {};
    for (int k = 0; k < Hn; k += 32) {
      bf16x8 a0 = ld8(ap + k);
      bf16x8 a1 = ld8(ap + 16 * Hn + k);
      bf16x8 w0 = ld8(bp + k);
      bf16x8 w1 = ld8(bp + 16 * Hn + k);
      acc[0][0] = mfma16(a0, w0, acc[0][0]);
      acc[0][1] = mfma16(a0, w1, acc[0][1]);
      acc[1][0] = mfma16(a1, w0, acc[1][0]);
      acc[1][1] = mfma16(a1, w1, acc[1][1]);
    }
#pragma unroll
    for (int rt = 0; rt < 2; ++rt)
#pragma unroll
      for (int ct = 0; ct < 2; ++ct)
#pragma unroll
        for (int r = 0; r < 4; ++r)
          pa[wave][rt * 16 + (lane >> 4) * 4 + r][ct * 16 + l15] = acc[rt][ct][r];
  }
  __syncthreads();
  const int bl = threadIdx.x >> 3;
  const int b = b0 + bl;
#pragma unroll
  for (int i = 0; i < 4; ++i) {
    const int jl = (threadIdx.x & 7) * 4 + i;
    const int j = j0 + jl;
    float z2 = sigm(pa[0][bl][jl] + PAg[(size_t)b * 1024 + j] + bhd[j] + bgv[j]);
    float r2 = sigm(pa[1][bl][jl] + PAg[(size_t)b * 1024 + 512 + j] + bhd[512 + j] + bgv[512 + j]);
    const size_t o = (size_t)b * Hn + j;
    float gvv = gf[o];
    float gc = tanh_f(pa[2][bl][jl] + bhd[1024 + j] + r2 * gvv);
    float gn = (1.0f - z2) * gvv + z2 * gc;
    gf[o] = gn;
    gb_out[o] = f2bf(gn);
    if (g_tail) g_tail[o] = gn;
  }
}

// ---------------- host ----------------
extern "C" void kernel_launch(void* const* d_in, const int* in_sizes, int n_in,
                              void* d_out, int out_size, void* d_ws, size_t ws_size,
                              hipStream_t stream) {
  const float* x   = (const float*)d_in[0];
  const float* h0  = (const float*)d_in[1];
  const float* g0  = (const float*)d_in[2];
  const float* Wx  = (const float*)d_in[3];
  const float* bx  = (const float*)d_in[4];
  const float* Wh  = (const float*)d_in[5];
  const float* bh  = (const float*)d_in[6];
  const float* Wgh = (const float*)d_in[7];
  const float* bgh = (const float*)d_in[8];
  const float* Whd = (const float*)d_in[9];
  const float* bhd = (const float*)d_in[10];
  const float* Wg  = (const float*)d_in[11];
  const float* bg  = (const float*)d_in[12];

  char* ws = (char*)d_ws;
  unsigned short* Whb  = (unsigned short*)(ws + 0);         // 1536x512 bf16
  unsigned short* Wghb = (unsigned short*)(ws + 1572864);   // 1536x512
  unsigned short* Whdb = (unsigned short*)(ws + 3145728);   // 1536x512
  unsigned short* Wgb  = (unsigned short*)(ws + 4718592);   // 1024x512
  unsigned short* Wxb  = (unsigned short*)(ws + 5767168);   // 2048x512
  unsigned short* hbA  = (unsigned short*)(ws + 7864320);   // 256x512
  unsigned short* hbB  = (unsigned short*)(ws + 8126464);   // 256x512
  unsigned short* gb_  = (unsigned short*)(ws + 8388608);   // 256x512
  unsigned short* hdb  = (unsigned short*)(ws + 8650752);   // 256x512
  float* gf            = (float*)(ws + 8912896);            // 256x512 fp32
  float* PAg           = (float*)(ws + 9437184);            // 256x1024 fp32
  unsigned short* xb   = (unsigned short*)(ws + 10485760);  // Tc*256*512 bf16

  const size_t FIXED = 10485760ULL;
  int Tc = 64;
  while (Tc > 1 && FIXED + (size_t)Tc * 2359296ULL > ws_size) Tc >>= 1;
  float* XP = (float*)(ws + FIXED + (size_t)Tc * 262144ULL);  // Tc*256*2048 fp32

  float* hs = (float*)d_out;
  float* h_tail = hs + (size_t)Tn * Bn * Hn;
  float* g_tail = h_tail + (size_t)Bn * Hn;

  // weight + state conversion
  cvt_kernel<<<dim3(512), 256, 0, stream>>>(Wh, Whb, 1536 * 512);
  cvt_kernel<<<dim3(512), 256, 0, stream>>>(Wgh, Wghb, 1536 * 512);
  cvt_kernel<<<dim3(512), 256, 0, stream>>>(Whd, Whdb, 1536 * 512);
  cvt_kernel<<<dim3(512), 256, 0, stream>>>(Wg, Wgb, 1024 * 512);
  cvt_kernel<<<dim3(512), 256, 0, stream>>>(Wx, Wxb, 2048 * 512);
  cvt_kernel<<<dim3(128), 256, 0, stream>>>(h0, hbA, Bn * Hn);
  cvt_kernel<<<dim3(128), 256, 0, stream>>>(g0, gb_, Bn * Hn);
  hipMemcpyAsync(gf, (const void*)g0, (size_t)Bn * Hn * 4, hipMemcpyDeviceToDevice, stream);

  const int nChunks = Tn / Tc;
  for (int c = 0; c < nChunks; ++c) {
    const int t0 = c * Tc;
    cvt_kernel<<<dim3(1024), 256, 0, stream>>>(x + (size_t)t0 * Bn * INn, xb, Tc * Bn * INn);
    xp_gemm_kernel<<<dim3(Tc * 4, 32), 256, 0, stream>>>(xb, Wxb, bx, bh, bgh, XP);
    for (int tt = 0; tt < Tc; ++tt) {
      const int t = t0 + tt;
      const float* hprev = (t == 0) ? h0 : hs + (size_t)(t - 1) * Bn * Hn;
      const unsigned short* hin = (t & 1) ? hbB : hbA;
      unsigned short* hout = (t & 1) ? hbA : hbB;
      phaseA_kernel<<<dim3(8, 16), 256, 0, stream>>>(
          Whb, Wghb, Wgb, hin, gb_, XP + (size_t)tt * Bn * 2048, gf, hprev,
          hs + (size_t)t * Bn * Hn, (t == Tn - 1) ? h_tail : nullptr, hout, hdb, PAg);
      phaseB_kernel<<<dim3(8, 16), 256, 0, stream>>>(
          Whdb, hdb, bhd, bg, PAg, gf, gb_, (t == Tn - 1) ? g_tail : nullptr);
    }
  }
}